// Round 1
// baseline (144.462 us; speedup 1.0000x reference)
//
#include <hip/hip_runtime.h>
#include <hip/hip_bf16.h>

// Prototypical nets head:
//   s_emb [64,16,2048] f32, q_emb [64,512,2048] f32
//   out = concat(log_p_y [64,512,64] f32, ce_loss f32, acc f32)

typedef __attribute__((ext_vector_type(8))) short bf16x8;
typedef __attribute__((ext_vector_type(4))) float f32x4;

#define N_WAY 64
#define N_SHOT 16
#define N_QUERY 512
#define DIM 2048
#define N_ROWS (N_WAY * N_QUERY)      // 32768
#define OUT_LOGP (N_ROWS * N_WAY)     // 2097152
#define KSLICES 8
#define KS (DIM / KSLICES)            // 256

static __device__ __forceinline__ short f2bf(float x) {
  union { __hip_bfloat16 b; short s; } u;
  u.b = __float2bfloat16(x);
  return u.s;
}

// ---------------------------------------------------------------------------
// Kernel 1: per-(way, k-slice) prototype mean -> bf16 proto table + partial sumsq
__global__ void proto_part(const float* __restrict__ s_emb,
                           __hip_bfloat16* __restrict__ proto,
                           float* __restrict__ c_part) {
  int b = blockIdx.x;          // 0..511
  int m = b >> 3;              // way 0..63
  int ks = b & 7;              // k-slice 0..7
  int t = threadIdx.x;         // 0..255
  int k = ks * KS + t;

  const float* base = s_emb + ((size_t)m * N_SHOT) * DIM + k;
  float s = 0.f;
#pragma unroll
  for (int j = 0; j < N_SHOT; ++j) s += base[(size_t)j * DIM];
  float p = s * (1.0f / N_SHOT);
  proto[m * DIM + k] = __float2bfloat16(p);

  float sq = p * p;
#pragma unroll
  for (int off = 1; off < 64; off <<= 1) sq += __shfl_xor(sq, off);

  __shared__ float red[4];
  int lane = t & 63, w = t >> 6;
  if (lane == 0) red[w] = sq;
  __syncthreads();
  if (t == 0) {
    c_part[m * KSLICES + ks] = red[0] + red[1] + red[2] + red[3];
  }
}

// ---------------------------------------------------------------------------
// Kernel 2: finalize c[m] = |p_m|^2 / D, zero the scalar output slots
__global__ void proto_fin(const float* __restrict__ c_part,
                          float* __restrict__ c,
                          float* __restrict__ scalars) {
  int t = threadIdx.x; // 64 threads
  if (t < N_WAY) {
    float s = 0.f;
#pragma unroll
    for (int i = 0; i < KSLICES; ++i) s += c_part[t * KSLICES + i];
    c[t] = s * (1.0f / DIM);
  }
  if (t < 2) scalars[t] = 0.f;
}

// ---------------------------------------------------------------------------
// Kernel 3: main. Each wave: 16 query rows x all 64 protos.
//   s_m = (2 q.p_m - |p_m|^2)/D ; log_p = s - lse(s) (sq_q cancels in softmax)
__launch_bounds__(256)
__global__ void dist_kernel(const float* __restrict__ q,
                            const __hip_bfloat16* __restrict__ proto,
                            const float* __restrict__ c,
                            float* __restrict__ out,
                            float* __restrict__ scalars) {
  int gtid = blockIdx.x * 256 + threadIdx.x;
  int wid = gtid >> 6;           // global wave id, 0..2047
  int lane = threadIdx.x & 63;
  int l15 = lane & 15;
  int g = lane >> 4;
  int rowbase = wid * 16;

  const float* qp = q + (size_t)(rowbase + l15) * DIM + g * 8;
  const short* pp = (const short*)proto + l15 * DIM + g * 8;

  f32x4 acc[4];
#pragma unroll
  for (int ct = 0; ct < 4; ++ct) acc[ct] = (f32x4){0.f, 0.f, 0.f, 0.f};

#pragma unroll 4
  for (int k = 0; k < DIM; k += 32) {
    float4 a0 = *reinterpret_cast<const float4*>(qp + k);
    float4 a1 = *reinterpret_cast<const float4*>(qp + k + 4);
    bf16x8 af;
    af[0] = f2bf(a0.x); af[1] = f2bf(a0.y); af[2] = f2bf(a0.z); af[3] = f2bf(a0.w);
    af[4] = f2bf(a1.x); af[5] = f2bf(a1.y); af[6] = f2bf(a1.z); af[7] = f2bf(a1.w);
#pragma unroll
    for (int ct = 0; ct < 4; ++ct) {
      bf16x8 bf = *reinterpret_cast<const bf16x8*>(pp + ct * (16 * DIM) + k);
      acc[ct] = __builtin_amdgcn_mfma_f32_16x16x32_bf16(af, bf, acc[ct], 0, 0, 0);
    }
  }

  // c for this lane's 4 columns (col = ct*16 + l15)
  float cc[4];
#pragma unroll
  for (int ct = 0; ct < 4; ++ct) cc[ct] = c[ct * 16 + l15];

  const float scale = 2.0f / (float)DIM;
  float ce_part = 0.f;
  float acc_part = 0.f;

#pragma unroll
  for (int r = 0; r < 4; ++r) {
    int row = rowbase + g * 4 + r;
    int w = row >> 9;            // true class = row / N_QUERY

    float s0 = acc[0][r] * scale - cc[0];
    float s1 = acc[1][r] * scale - cc[1];
    float s2 = acc[2][r] * scale - cc[2];
    float s3 = acc[3][r] * scale - cc[3];

    // row max across 4 local cols + 16 lanes of this group
    float mx = fmaxf(fmaxf(s0, s1), fmaxf(s2, s3));
#pragma unroll
    for (int off = 1; off < 16; off <<= 1) mx = fmaxf(mx, __shfl_xor(mx, off));

    float e = __expf(s0 - mx) + __expf(s1 - mx) + __expf(s2 - mx) + __expf(s3 - mx);
#pragma unroll
    for (int off = 1; off < 16; off <<= 1) e += __shfl_xor(e, off);
    float lse = mx + __logf(e);

    size_t ob = (size_t)row * N_WAY + l15;
    out[ob]      = s0 - lse;
    out[ob + 16] = s1 - lse;
    out[ob + 32] = s2 - lse;
    out[ob + 48] = s3 - lse;

    // CE: -log_p[row, w] = lse - s_w ; col ct*16+l15 == w
    if (l15 == (w & 15)) {
      int ct = w >> 4;
      float sw = (ct == 0) ? s0 : (ct == 1) ? s1 : (ct == 2) ? s2 : s3;
      ce_part += lse - sw;
    }

    // argmax with first-occurrence tie-break
    float bv = s0; int bi = l15;
    if (s1 > bv) { bv = s1; bi = l15 + 16; }
    if (s2 > bv) { bv = s2; bi = l15 + 32; }
    if (s3 > bv) { bv = s3; bi = l15 + 48; }
#pragma unroll
    for (int off = 1; off < 16; off <<= 1) {
      float ov = __shfl_xor(bv, off);
      int oi = __shfl_xor(bi, off);
      if (ov > bv || (ov == bv && oi < bi)) { bv = ov; bi = oi; }
    }
    if (l15 == 0) acc_part += (bi == w) ? 1.0f : 0.0f;
  }

  // full-wave reduce of scalar partials, one atomic pair per wave
#pragma unroll
  for (int off = 1; off < 64; off <<= 1) {
    ce_part += __shfl_xor(ce_part, off);
    acc_part += __shfl_xor(acc_part, off);
  }
  if (lane == 0) {
    atomicAdd(&scalars[0], ce_part * (1.0f / N_ROWS));
    atomicAdd(&scalars[1], acc_part * (1.0f / N_ROWS));
  }
}

// ---------------------------------------------------------------------------
extern "C" void kernel_launch(void* const* d_in, const int* in_sizes, int n_in,
                              void* d_out, int out_size, void* d_ws, size_t ws_size,
                              hipStream_t stream) {
  const float* s_emb = (const float*)d_in[0];
  const float* q_emb = (const float*)d_in[1];
  float* out = (float*)d_out;
  char* ws = (char*)d_ws;

  __hip_bfloat16* proto = (__hip_bfloat16*)ws;                 // 256 KB
  float* c_part = (float*)(ws + 256 * 1024);                   // 2 KB
  float* c = (float*)(ws + 256 * 1024 + 4096);                 // 256 B
  float* scalars = out + OUT_LOGP;

  hipLaunchKernelGGL(proto_part, dim3(512), dim3(256), 0, stream, s_emb, proto, c_part);
  hipLaunchKernelGGL(proto_fin, dim3(1), dim3(64), 0, stream, c_part, c, scalars);
  hipLaunchKernelGGL(dist_kernel, dim3(512), dim3(256), 0, stream,
                     q_emb, proto, c, out, scalars);
}